// Round 1
// baseline (206.962 us; speedup 1.0000x reference)
//
#include <hip/hip_runtime.h>
#include <hip/hip_bf16.h>
#include <stdint.h>

#define IN_FEATS 128
#define TWO_IN   256
#define HIDDEN   128

// 0: A/B fragment K-mapping k = 8*(lane>>4)+i (contiguous 8)
// 1: k = 4*(lane>>4)+i (i<4) and 16+4*(lane>>4)+(i-4) (glued 16x16x16 halves)
#define K_SPLIT 0

typedef __attribute__((ext_vector_type(8))) __bf16 bf16x8;
typedef __attribute__((ext_vector_type(4))) __bf16 bf16x4;
typedef __attribute__((ext_vector_type(4))) float f32x4;

__device__ __forceinline__ float bf_lo(uint32_t u) { return __uint_as_float(u << 16); }
__device__ __forceinline__ float bf_hi(uint32_t u) { return __uint_as_float(u & 0xffff0000u); }
__device__ __forceinline__ ushort f2bf(float f) {
  uint32_t u = __float_as_uint(f);
  uint32_t r = (u + 0x7fffu + ((u >> 16) & 1u)) >> 16;  // RNE
  return (ushort)r;
}

// ---------------- prep: h fp32 -> bf16 (pad rows zeroed) ----------------
__global__ void cvt_h_kernel(const float* __restrict__ h, ushort* __restrict__ hb,
                             int n_valid, int n_total) {
  int i = blockIdx.x * blockDim.x + threadIdx.x;
  int stride = gridDim.x * blockDim.x;
  for (int j = i; j < (n_total >> 2); j += stride) {
    int base = j << 2;
    ushort4 o;
    if (base < n_valid) {
      float4 v = *(const float4*)(h + base);
      o.x = f2bf(v.x); o.y = f2bf(v.y); o.z = f2bf(v.z); o.w = f2bf(v.w);
    } else {
      o.x = 0; o.y = 0; o.z = 0; o.w = 0;
    }
    *(ushort4*)(hb + base) = o;
  }
}

// ---------------- prep: W1 -> B[n][k] bf16, n<128: W1a, n>=128: W1b ----------------
__global__ void cvt_w1_kernel(const float* __restrict__ W1, ushort* __restrict__ Bm) {
  int t = blockIdx.x * blockDim.x + threadIdx.x;
  if (t >= TWO_IN * IN_FEATS) return;
  int n = t >> 7, k = t & 127;
  float v = (n < HIDDEN) ? W1[n * TWO_IN + k]
                         : W1[(n - HIDDEN) * TWO_IN + IN_FEATS + k];
  Bm[t] = f2bf(v);
}

// ---------------- GEMM: P[M][256] = h_bf[M][128] @ Bm[256][128]^T ----------------
// 128x128 tile per block, K=128 in one LDS residency. 4 waves, each 64x64.
__global__ __launch_bounds__(256, 2)
void gemm_kernel(const ushort* __restrict__ A, const ushort* __restrict__ B,
                 ushort* __restrict__ P, int M) {
  __shared__ __align__(16) ushort lds[2 * 128 * 128];  // 64 KB: A tile | B tile
  const int tid  = threadIdx.x;
  const int lane = tid & 63;
  const int w    = tid >> 6;
  const int bm = blockIdx.x, bn = blockIdx.y;

  const char* Asrc = (const char*)(A + (size_t)bm * 128 * IN_FEATS);
  const char* Bsrc = (const char*)(B + (size_t)bn * 128 * IN_FEATS);
  char* ldsA = (char*)lds;
  char* ldsB = (char*)lds + 32768;

  // Stage 32KB A + 32KB B. LDS dest linear (base + lane*16), global source
  // inverse-swizzled so that swizzled ds_reads below see logical layout.
  #pragma unroll
  for (int it = 0; it < 8; ++it) {
    int idx = it * 256 + tid;                 // 16B chunk id, 0..2047
    int row = idx >> 4;                       // 256 B per row
    int scb = ((idx & 15) << 4) ^ ((row & 7) << 4);
    int goff = row * 256 + scb;
    int ldsoff = it * 4096 + w * 1024;        // wave-uniform; HW adds lane*16
    __builtin_amdgcn_global_load_lds(
        (const __attribute__((address_space(1))) void*)(Asrc + goff),
        (__attribute__((address_space(3))) void*)(ldsA + ldsoff), 16, 0, 0);
    __builtin_amdgcn_global_load_lds(
        (const __attribute__((address_space(1))) void*)(Bsrc + goff),
        (__attribute__((address_space(3))) void*)(ldsB + ldsoff), 16, 0, 0);
  }
  __syncthreads();

  const int wr = w >> 1, wc = w & 1;
  f32x4 acc[4][4] = {};

  #pragma unroll
  for (int kk = 0; kk < 4; ++kk) {
    bf16x8 af[4], bfr[4];
#if K_SPLIT == 0
    const int kb = kk * 64 + ((lane >> 4) << 4);   // byte offset of this lane's k-group
    #pragma unroll
    for (int m = 0; m < 4; ++m) {
      int row = wr * 64 + m * 16 + (lane & 15);
      af[m] = *(const bf16x8*)(ldsA + row * 256 + (kb ^ ((row & 7) << 4)));
    }
    #pragma unroll
    for (int n = 0; n < 4; ++n) {
      int row = wc * 64 + n * 16 + (lane & 15);
      bfr[n] = *(const bf16x8*)(ldsB + row * 256 + (kb ^ ((row & 7) << 4)));
    }
#else
    const int kb0 = kk * 64 + ((lane >> 4) << 3);        // lower 4 elems
    const int kb1 = kb0 + 32;                            // upper 4 (k+16)
    #pragma unroll
    for (int m = 0; m < 4; ++m) {
      int row = wr * 64 + m * 16 + (lane & 15);
      int sw = (row & 7) << 4;
      bf16x4 lo = *(const bf16x4*)(ldsA + row * 256 + (kb0 ^ sw));
      bf16x4 hi = *(const bf16x4*)(ldsA + row * 256 + (kb1 ^ sw));
      af[m] = bf16x8{lo[0],lo[1],lo[2],lo[3],hi[0],hi[1],hi[2],hi[3]};
    }
    #pragma unroll
    for (int n = 0; n < 4; ++n) {
      int row = wc * 64 + n * 16 + (lane & 15);
      int sw = (row & 7) << 4;
      bf16x4 lo = *(const bf16x4*)(ldsB + row * 256 + (kb0 ^ sw));
      bf16x4 hi = *(const bf16x4*)(ldsB + row * 256 + (kb1 ^ sw));
      bfr[n] = bf16x8{lo[0],lo[1],lo[2],lo[3],hi[0],hi[1],hi[2],hi[3]};
    }
#endif
    #pragma unroll
    for (int m = 0; m < 4; ++m)
      #pragma unroll
      for (int n = 0; n < 4; ++n)
        acc[m][n] = __builtin_amdgcn_mfma_f32_16x16x32_bf16(af[m], bfr[n], acc[m][n], 0, 0, 0);
  }

  // Epilogue: stage bf16 tile in LDS (pad row to 136 shorts), coalesced 16B stores.
  __syncthreads();
  ushort* outLds = (ushort*)lds;
  #pragma unroll
  for (int m = 0; m < 4; ++m) {
    #pragma unroll
    for (int n = 0; n < 4; ++n) {
      int col = wc * 64 + n * 16 + (lane & 15);
      #pragma unroll
      for (int r = 0; r < 4; ++r) {
        int row = wr * 64 + m * 16 + ((lane >> 4) << 2) + r;
        outLds[row * 136 + col] = f2bf(acc[m][n][r]);
      }
    }
  }
  __syncthreads();
  const int mleft = M - bm * 128;
  #pragma unroll
  for (int it = 0; it < 8; ++it) {
    int idx = it * 256 + tid;
    int row = idx >> 4, c = idx & 15;
    if (row < mleft) {
      bf16x8 v = *(const bf16x8*)(outLds + row * 136 + c * 8);
      *(bf16x8*)((char*)P + (size_t)(bm * 128 + row) * 512 + bn * 256 + c * 16) = v;
    }
  }
}

// ---------------- edge phase: one wave per edge ----------------
// hidden[j] = relu(P[s][j] + P[d][128+j] + b1[j]); out = sigmoid(hidden . W2 + b2)
__global__ __launch_bounds__(256)
void edge_kernel(const int* __restrict__ src, const int* __restrict__ dst,
                 const ushort* __restrict__ P, const float* __restrict__ b1,
                 const float* __restrict__ W2, const float* __restrict__ b2,
                 float* __restrict__ out, int nE) {
  const int lane = threadIdx.x & 63;
  const int wid  = blockIdx.x * (blockDim.x >> 6) + (threadIdx.x >> 6);
  const int nw   = gridDim.x * (blockDim.x >> 6);
  const float2 b1v = ((const float2*)b1)[lane];   // feats 2l, 2l+1
  const float2 w2v = ((const float2*)W2)[lane];
  const float  b2s = *b2;
  for (int e = wid; e < nE; e += nw) {
    const int s = src[e], d = dst[e];
    uint32_t pa = *(const uint32_t*)(P + (size_t)s * 256 + 2 * lane);
    uint32_t pb = *(const uint32_t*)(P + (size_t)d * 256 + 128 + 2 * lane);
    float h0 = fmaxf(bf_lo(pa) + bf_lo(pb) + b1v.x, 0.0f);
    float h1 = fmaxf(bf_hi(pa) + bf_hi(pb) + b1v.y, 0.0f);
    float p = fmaf(h0, w2v.x, h1 * w2v.y);
    p += __shfl_xor(p, 32); p += __shfl_xor(p, 16); p += __shfl_xor(p, 8);
    p += __shfl_xor(p, 4);  p += __shfl_xor(p, 2);  p += __shfl_xor(p, 1);
    if (lane == 0) out[e] = 1.0f / (1.0f + __expf(-(p + b2s)));
  }
}

extern "C" void kernel_launch(void* const* d_in, const int* in_sizes, int n_in,
                              void* d_out, int out_size, void* d_ws, size_t ws_size,
                              hipStream_t stream) {
  const int*   src = (const int*)d_in[0];
  const int*   dst = (const int*)d_in[1];
  const float* h   = (const float*)d_in[2];
  const float* W1  = (const float*)d_in[3];
  const float* b1  = (const float*)d_in[4];
  const float* W2  = (const float*)d_in[5];
  const float* b2  = (const float*)d_in[6];
  float* out = (float*)d_out;
  const int nE = in_sizes[0];
  const int nN = in_sizes[2] / IN_FEATS;
  const int Mpad = (nN + 127) & ~127;

  char* ws = (char*)d_ws;
  ushort* h_bf = (ushort*)ws;
  size_t off = (size_t)Mpad * IN_FEATS * sizeof(ushort);
  ushort* Bm = (ushort*)(ws + off);
  off += (size_t)TWO_IN * IN_FEATS * sizeof(ushort);
  ushort* P = (ushort*)(ws + off);
  // total ws use: ~25.6MB + 64KB + 51.2MB ~= 77 MB

  const int n_valid = nN * IN_FEATS, n_total = Mpad * IN_FEATS;
  hipLaunchKernelGGL(cvt_h_kernel, dim3(1024), dim3(256), 0, stream, h, h_bf, n_valid, n_total);
  hipLaunchKernelGGL(cvt_w1_kernel, dim3((TWO_IN * IN_FEATS + 255) / 256), dim3(256), 0, stream, W1, Bm);
  hipLaunchKernelGGL(gemm_kernel, dim3(Mpad / 128, 2), dim3(256), 0, stream, h_bf, Bm, P, nN);
  hipLaunchKernelGGL(edge_kernel, dim3(2048), dim3(256), 0, stream, src, dst, P, b1, W2, b2, out, nE);
}

// Round 2
// 166.189 us; speedup vs baseline: 1.2453x; 1.2453x over previous
//
#include <hip/hip_runtime.h>
#include <hip/hip_bf16.h>
#include <stdint.h>

#define IN_FEATS 128
#define TWO_IN   256
#define HIDDEN   128

typedef __attribute__((ext_vector_type(8))) __bf16 bf16x8;
typedef __attribute__((ext_vector_type(4))) float f32x4;

__device__ __forceinline__ float bf_lo(uint32_t u) { return __uint_as_float(u << 16); }
__device__ __forceinline__ float bf_hi(uint32_t u) { return __uint_as_float(u & 0xffff0000u); }
__device__ __forceinline__ ushort f2bf(float f) {
  uint32_t u = __float_as_uint(f);
  uint32_t r = (u + 0x7fffu + ((u >> 16) & 1u)) >> 16;  // RNE
  return (ushort)r;
}

// ---------------- prep: h fp32 -> bf16 (pad rows zeroed) ----------------
__global__ void cvt_h_kernel(const float* __restrict__ h, ushort* __restrict__ hb,
                             int n_valid, int n_total) {
  int i = blockIdx.x * blockDim.x + threadIdx.x;
  int stride = gridDim.x * blockDim.x;
  for (int j = i; j < (n_total >> 2); j += stride) {
    int base = j << 2;
    ushort4 o;
    if (base < n_valid) {
      float4 v = *(const float4*)(h + base);
      o.x = f2bf(v.x); o.y = f2bf(v.y); o.z = f2bf(v.z); o.w = f2bf(v.w);
    } else {
      o.x = 0; o.y = 0; o.z = 0; o.w = 0;
    }
    *(ushort4*)(hb + base) = o;
  }
}

// ---------------- prep: W1 -> B[n][k] bf16, n<128: W1a, n>=128: W1b ----------------
__global__ void cvt_w1_kernel(const float* __restrict__ W1, ushort* __restrict__ Bm) {
  int t = blockIdx.x * blockDim.x + threadIdx.x;
  if (t >= TWO_IN * IN_FEATS) return;
  int n = t >> 7, k = t & 127;
  float v = (n < HIDDEN) ? W1[n * TWO_IN + k]
                         : W1[(n - HIDDEN) * TWO_IN + IN_FEATS + k];
  Bm[t] = f2bf(v);
}

// ---------------- GEMM: P[M][256] = h_bf[M][128] @ Bm[256][128]^T  (+0.5*b1 folded) ----
__global__ __launch_bounds__(256, 2)
void gemm_kernel(const ushort* __restrict__ A, const ushort* __restrict__ B,
                 const float* __restrict__ b1, ushort* __restrict__ P, int M) {
  __shared__ __align__(16) ushort lds[2 * 128 * 128];  // 64 KB: A tile | B tile
  const int tid  = threadIdx.x;
  const int lane = tid & 63;
  const int w    = tid >> 6;
  const int bm = blockIdx.x, bn = blockIdx.y;

  const char* Asrc = (const char*)(A + (size_t)bm * 128 * IN_FEATS);
  const char* Bsrc = (const char*)(B + (size_t)bn * 128 * IN_FEATS);
  char* ldsA = (char*)lds;
  char* ldsB = (char*)lds + 32768;

  #pragma unroll
  for (int it = 0; it < 8; ++it) {
    int idx = it * 256 + tid;                 // 16B chunk id, 0..2047
    int row = idx >> 4;                       // 256 B per row
    int scb = ((idx & 15) << 4) ^ ((row & 7) << 4);
    int goff = row * 256 + scb;
    int ldsoff = it * 4096 + w * 1024;        // wave-uniform; HW adds lane*16
    __builtin_amdgcn_global_load_lds(
        (const __attribute__((address_space(1))) void*)(Asrc + goff),
        (__attribute__((address_space(3))) void*)(ldsA + ldsoff), 16, 0, 0);
    __builtin_amdgcn_global_load_lds(
        (const __attribute__((address_space(1))) void*)(Bsrc + goff),
        (__attribute__((address_space(3))) void*)(ldsB + ldsoff), 16, 0, 0);
  }
  __syncthreads();

  const int wr = w >> 1, wc = w & 1;
  f32x4 acc[4][4] = {};

  #pragma unroll
  for (int kk = 0; kk < 4; ++kk) {
    bf16x8 af[4], bfr[4];
    const int kb = kk * 64 + ((lane >> 4) << 4);   // byte offset of this lane's k-group
    #pragma unroll
    for (int m = 0; m < 4; ++m) {
      int row = wr * 64 + m * 16 + (lane & 15);
      af[m] = *(const bf16x8*)(ldsA + row * 256 + (kb ^ ((row & 7) << 4)));
    }
    #pragma unroll
    for (int n = 0; n < 4; ++n) {
      int row = wc * 64 + n * 16 + (lane & 15);
      bfr[n] = *(const bf16x8*)(ldsB + row * 256 + (kb ^ ((row & 7) << 4)));
    }
    #pragma unroll
    for (int m = 0; m < 4; ++m)
      #pragma unroll
      for (int n = 0; n < 4; ++n)
        acc[m][n] = __builtin_amdgcn_mfma_f32_16x16x32_bf16(af[m], bfr[n], acc[m][n], 0, 0, 0);
  }

  // bias fold: P += 0.5*b1[col_local] (both halves reconstruct b1 when summed)
  float bias[4];
  #pragma unroll
  for (int n = 0; n < 4; ++n) bias[n] = 0.5f * b1[wc * 64 + n * 16 + (lane & 15)];

  __syncthreads();
  ushort* outLds = (ushort*)lds;
  #pragma unroll
  for (int m = 0; m < 4; ++m) {
    #pragma unroll
    for (int n = 0; n < 4; ++n) {
      int col = wc * 64 + n * 16 + (lane & 15);
      #pragma unroll
      for (int r = 0; r < 4; ++r) {
        int row = wr * 64 + m * 16 + ((lane >> 4) << 2) + r;
        outLds[row * 136 + col] = f2bf(acc[m][n][r] + bias[n]);
      }
    }
  }
  __syncthreads();
  const int mleft = M - bm * 128;
  #pragma unroll
  for (int it = 0; it < 8; ++it) {
    int idx = it * 256 + tid;
    int row = idx >> 4, c = idx & 15;
    if (row < mleft) {
      bf16x8 v = *(const bf16x8*)(outLds + row * 136 + c * 8);
      *(bf16x8*)((char*)P + (size_t)(bm * 128 + row) * 512 + bn * 256 + c * 16) = v;
    }
  }
}

// ---------------- edge phase: 16 lanes/edge, 4 edges/wave ----------------
// hidden[j] = relu(P[s][j] + P[d][128+j]); out = sigmoid(hidden . W2 + b2)
// (b1 already folded into P by gemm epilogue)
__global__ __launch_bounds__(256)
void edge_kernel(const int* __restrict__ src, const int* __restrict__ dst,
                 const ushort* __restrict__ P,
                 const float* __restrict__ W2, const float* __restrict__ b2,
                 float* __restrict__ out, int nE) {
  const int lane = threadIdx.x & 63;
  const int t = lane & 15;          // sublane: feats [t*8, t*8+8)
  const int g = lane >> 4;          // edge slot within wave
  const int wid = blockIdx.x * (blockDim.x >> 6) + (threadIdx.x >> 6);
  const int nw  = gridDim.x * (blockDim.x >> 6);
  const float4 w2a = ((const float4*)W2)[2 * t];
  const float4 w2b = ((const float4*)W2)[2 * t + 1];
  const float b2s = *b2;

  #pragma unroll 2
  for (int e0 = wid * 4; e0 < nE; e0 += nw * 4) {
    int e = e0 + g;
    bool valid = e < nE;
    int ec = valid ? e : nE - 1;
    int s = src[ec], d = dst[ec];
    uint4 pa = *(const uint4*)(P + (size_t)s * 256 + t * 8);
    uint4 pb = *(const uint4*)(P + (size_t)d * 256 + 128 + t * 8);
    float acc;
    acc = fmaxf(bf_lo(pa.x) + bf_lo(pb.x), 0.0f) * w2a.x;
    acc = fmaf(fmaxf(bf_hi(pa.x) + bf_hi(pb.x), 0.0f), w2a.y, acc);
    acc = fmaf(fmaxf(bf_lo(pa.y) + bf_lo(pb.y), 0.0f), w2a.z, acc);
    acc = fmaf(fmaxf(bf_hi(pa.y) + bf_hi(pb.y), 0.0f), w2a.w, acc);
    acc = fmaf(fmaxf(bf_lo(pa.z) + bf_lo(pb.z), 0.0f), w2b.x, acc);
    acc = fmaf(fmaxf(bf_hi(pa.z) + bf_hi(pb.z), 0.0f), w2b.y, acc);
    acc = fmaf(fmaxf(bf_lo(pa.w) + bf_lo(pb.w), 0.0f), w2b.z, acc);
    acc = fmaf(fmaxf(bf_hi(pa.w) + bf_hi(pb.w), 0.0f), w2b.w, acc);
    acc += __shfl_xor(acc, 8);
    acc += __shfl_xor(acc, 4);
    acc += __shfl_xor(acc, 2);
    acc += __shfl_xor(acc, 1);
    if (t == 0 && valid) out[e] = 1.0f / (1.0f + __expf(-(acc + b2s)));
  }
}

extern "C" void kernel_launch(void* const* d_in, const int* in_sizes, int n_in,
                              void* d_out, int out_size, void* d_ws, size_t ws_size,
                              hipStream_t stream) {
  const int*   src = (const int*)d_in[0];
  const int*   dst = (const int*)d_in[1];
  const float* h   = (const float*)d_in[2];
  const float* W1  = (const float*)d_in[3];
  const float* b1  = (const float*)d_in[4];
  const float* W2  = (const float*)d_in[5];
  const float* b2  = (const float*)d_in[6];
  float* out = (float*)d_out;
  const int nE = in_sizes[0];
  const int nN = in_sizes[2] / IN_FEATS;
  const int Mpad = (nN + 127) & ~127;

  char* ws = (char*)d_ws;
  ushort* h_bf = (ushort*)ws;
  size_t off = (size_t)Mpad * IN_FEATS * sizeof(ushort);
  ushort* Bm = (ushort*)(ws + off);
  off += (size_t)TWO_IN * IN_FEATS * sizeof(ushort);
  ushort* P = (ushort*)(ws + off);

  const int n_valid = nN * IN_FEATS, n_total = Mpad * IN_FEATS;
  hipLaunchKernelGGL(cvt_h_kernel, dim3(2048), dim3(256), 0, stream, h, h_bf, n_valid, n_total);
  hipLaunchKernelGGL(cvt_w1_kernel, dim3((TWO_IN * IN_FEATS + 255) / 256), dim3(256), 0, stream, W1, Bm);
  hipLaunchKernelGGL(gemm_kernel, dim3(Mpad / 128, 2), dim3(256), 0, stream, h_bf, Bm, b1, P, nN);
  hipLaunchKernelGGL(edge_kernel, dim3(4096), dim3(256), 0, stream, src, dst, P, W2, b2, out, nE);
}

// Round 3
// 157.896 us; speedup vs baseline: 1.3107x; 1.0525x over previous
//
#include <hip/hip_runtime.h>
#include <hip/hip_bf16.h>
#include <stdint.h>

#define IN_FEATS 128
#define TWO_IN   256
#define HIDDEN   128

typedef __attribute__((ext_vector_type(8))) __bf16 bf16x8;
typedef __attribute__((ext_vector_type(8))) ushort u16x8;
typedef __attribute__((ext_vector_type(4))) float f32x4;

__device__ __forceinline__ float bf_lo(uint32_t u) { return __uint_as_float(u << 16); }
__device__ __forceinline__ float bf_hi(uint32_t u) { return __uint_as_float(u & 0xffff0000u); }
__device__ __forceinline__ ushort f2bf(float f) {
  uint32_t u = __float_as_uint(f);
  uint32_t r = (u + 0x7fffu + ((u >> 16) & 1u)) >> 16;  // RNE
  return (ushort)r;
}

// ---------------- prep: W1 -> Bm[n][k] bf16 (n<128: W1a, n>=128: W1b) ----------------
__global__ void cvt_w1_kernel(const float* __restrict__ W1, ushort* __restrict__ Bm) {
  int t = blockIdx.x * blockDim.x + threadIdx.x;
  if (t >= TWO_IN * IN_FEATS) return;
  int n = t >> 7, k = t & 127;
  float v = (n < HIDDEN) ? W1[n * TWO_IN + k]
                         : W1[(n - HIDDEN) * TWO_IN + IN_FEATS + k];
  Bm[t] = f2bf(v);
}

// ---------------- fused GEMM: P[M][256] = bf16(h)[M][128] @ Bm[256][128]^T + 0.5*b1 ----
// 128x256 tile per block (full N), 8 waves (2x4), h fp32 read ONCE and converted in-kernel.
__global__ __launch_bounds__(512, 1)
void gemm_fused_kernel(const float* __restrict__ h, const ushort* __restrict__ Bm,
                       const float* __restrict__ b1, ushort* __restrict__ P, int M) {
  __shared__ __align__(16) ushort lds[(128 + 256) * 128];  // 96KB: A 32KB | B 64KB
  const int tid  = threadIdx.x;      // 0..511
  const int lane = tid & 63;
  const int w    = tid >> 6;         // 0..7
  const int bm   = blockIdx.x;
  const int m0   = bm * 128;

  char* ldsA = (char*)lds;                  // 128 rows x 256B (swizzled)
  char* ldsB = (char*)lds + 32768;          // 256 rows x 256B (swizzled)

  // --- stage B via global_load_lds (source pre-swizzled, LDS dest linear) ---
  const char* Bsrc = (const char*)Bm;
  #pragma unroll
  for (int it = 0; it < 8; ++it) {
    int idx = it * 512 + tid;               // 16B chunk id, 0..4095
    int row = idx >> 4;                     // 0..255
    int scb = ((idx & 15) << 4) ^ ((row & 7) << 4);
    int goff = row * 256 + scb;
    int ldsoff = it * 8192 + w * 1024;      // wave-uniform; HW adds lane*16
    __builtin_amdgcn_global_load_lds(
        (const __attribute__((address_space(1))) void*)(Bsrc + goff),
        (__attribute__((address_space(3))) void*)(ldsB + ldsoff), 16, 0, 0);
  }

  // --- stage A: h fp32 -> bf16, reg-staged, swizzled ds_write_b128 ---
  #pragma unroll
  for (int it = 0; it < 4; ++it) {
    int idx = it * 512 + tid;               // 0..2047 (128 rows x 16 chunks)
    int row = idx >> 4;
    int c   = idx & 15;                     // chunk of 8 floats
    int grow = m0 + row;
    float4 v0 = {0, 0, 0, 0}, v1 = {0, 0, 0, 0};
    if (grow < M) {
      const float* src = h + (size_t)grow * IN_FEATS + c * 8;
      v0 = *(const float4*)(src);
      v1 = *(const float4*)(src + 4);
    }
    u16x8 o;
    o[0] = f2bf(v0.x); o[1] = f2bf(v0.y); o[2] = f2bf(v0.z); o[3] = f2bf(v0.w);
    o[4] = f2bf(v1.x); o[5] = f2bf(v1.y); o[6] = f2bf(v1.z); o[7] = f2bf(v1.w);
    *(u16x8*)(ldsA + row * 256 + ((c * 16) ^ ((row & 7) << 4))) = o;
  }
  __syncthreads();

  const int wr = w >> 2, wc = w & 3;        // wave tile: 64 rows x 64 cols
  f32x4 acc[4][4] = {};

  #pragma unroll
  for (int kk = 0; kk < 4; ++kk) {
    bf16x8 af[4], bfr[4];
    const int kb = kk * 64 + ((lane >> 4) << 4);
    #pragma unroll
    for (int m = 0; m < 4; ++m) {
      int row = wr * 64 + m * 16 + (lane & 15);
      af[m] = *(const bf16x8*)(ldsA + row * 256 + (kb ^ ((row & 7) << 4)));
    }
    #pragma unroll
    for (int n = 0; n < 4; ++n) {
      int row = wc * 64 + n * 16 + (lane & 15);
      bfr[n] = *(const bf16x8*)(ldsB + row * 256 + (kb ^ ((row & 7) << 4)));
    }
    #pragma unroll
    for (int m = 0; m < 4; ++m)
      #pragma unroll
      for (int n = 0; n < 4; ++n)
        acc[m][n] = __builtin_amdgcn_mfma_f32_16x16x32_bf16(af[m], bfr[n], acc[m][n], 0, 0, 0);
  }

  // bias fold: P += 0.5*b1[col & 127] (src-half + dst-half reconstruct b1)
  float bias[4];
  #pragma unroll
  for (int n = 0; n < 4; ++n) {
    int col = wc * 64 + n * 16 + (lane & 15);
    bias[n] = 0.5f * b1[col & 127];
  }

  __syncthreads();
  ushort* outLds = (ushort*)lds;            // 128 rows x 264 shorts (66KB)
  #pragma unroll
  for (int m = 0; m < 4; ++m) {
    #pragma unroll
    for (int n = 0; n < 4; ++n) {
      int col = wc * 64 + n * 16 + (lane & 15);
      #pragma unroll
      for (int r = 0; r < 4; ++r) {
        int row = wr * 64 + m * 16 + ((lane >> 4) << 2) + r;
        outLds[row * 264 + col] = f2bf(acc[m][n][r] + bias[n]);
      }
    }
  }
  __syncthreads();
  const int mleft = M - m0;
  #pragma unroll
  for (int it = 0; it < 8; ++it) {
    int idx = it * 512 + tid;               // 16B chunk, 0..4095
    int row = idx >> 5;                     // 32 chunks per 512B row
    int c   = idx & 31;
    if (row < mleft)
      *(u16x8*)((char*)P + (size_t)(m0 + row) * 512 + c * 16) =
          *(const u16x8*)(outLds + row * 264 + c * 8);
  }
}

// ---------------- edge phase: 16 lanes/edge, 4 edges/wave, contiguous spans ----------------
__global__ __launch_bounds__(256)
void edge_kernel(const int* __restrict__ src, const int* __restrict__ dst,
                 const ushort* __restrict__ P,
                 const float* __restrict__ W2, const float* __restrict__ b2,
                 float* __restrict__ out, int nE, int qpw) {
  const int lane = threadIdx.x & 63;
  const int t = lane & 15;          // sublane: feats [t*8, t*8+8)
  const int g = lane >> 4;          // edge slot within wave
  const int wid = blockIdx.x * (blockDim.x >> 6) + (threadIdx.x >> 6);
  const float4 w2a = ((const float4*)W2)[2 * t];
  const float4 w2b = ((const float4*)W2)[2 * t + 1];
  const float b2s = *b2;

  const int Q = (nE + 3) >> 2;
  int q0 = wid * qpw;
  int qe = min(q0 + qpw, Q);
  #pragma unroll 4
  for (int q = q0; q < qe; ++q) {
    int e = q * 4 + g;
    bool valid = e < nE;
    int ec = valid ? e : nE - 1;
    int s = src[ec], d = dst[ec];
    uint4 pa = *(const uint4*)(P + (size_t)s * 256 + t * 8);
    uint4 pb = *(const uint4*)(P + (size_t)d * 256 + 128 + t * 8);
    float acc;
    acc = fmaxf(bf_lo(pa.x) + bf_lo(pb.x), 0.0f) * w2a.x;
    acc = fmaf(fmaxf(bf_hi(pa.x) + bf_hi(pb.x), 0.0f), w2a.y, acc);
    acc = fmaf(fmaxf(bf_lo(pa.y) + bf_lo(pb.y), 0.0f), w2a.z, acc);
    acc = fmaf(fmaxf(bf_hi(pa.y) + bf_hi(pb.y), 0.0f), w2a.w, acc);
    acc = fmaf(fmaxf(bf_lo(pa.z) + bf_lo(pb.z), 0.0f), w2b.x, acc);
    acc = fmaf(fmaxf(bf_hi(pa.z) + bf_hi(pb.z), 0.0f), w2b.y, acc);
    acc = fmaf(fmaxf(bf_lo(pa.w) + bf_lo(pb.w), 0.0f), w2b.z, acc);
    acc = fmaf(fmaxf(bf_hi(pa.w) + bf_hi(pb.w), 0.0f), w2b.w, acc);
    acc += __shfl_xor(acc, 8);
    acc += __shfl_xor(acc, 4);
    acc += __shfl_xor(acc, 2);
    acc += __shfl_xor(acc, 1);
    if (t == 0 && valid) out[e] = 1.0f / (1.0f + __expf(-(acc + b2s)));
  }
}

extern "C" void kernel_launch(void* const* d_in, const int* in_sizes, int n_in,
                              void* d_out, int out_size, void* d_ws, size_t ws_size,
                              hipStream_t stream) {
  const int*   src = (const int*)d_in[0];
  const int*   dst = (const int*)d_in[1];
  const float* h   = (const float*)d_in[2];
  const float* W1  = (const float*)d_in[3];
  const float* b1  = (const float*)d_in[4];
  const float* W2  = (const float*)d_in[5];
  const float* b2  = (const float*)d_in[6];
  float* out = (float*)d_out;
  const int nE = in_sizes[0];
  const int nN = in_sizes[2] / IN_FEATS;
  const int nBlocksM = (nN + 127) / 128;

  char* ws = (char*)d_ws;
  ushort* Bm = (ushort*)ws;                       // 64KB
  ushort* P  = (ushort*)(ws + 65536);             // nN*512 B  (~51.2MB)

  hipLaunchKernelGGL(cvt_w1_kernel, dim3((TWO_IN * IN_FEATS + 255) / 256), dim3(256), 0, stream, W1, Bm);
  hipLaunchKernelGGL(gemm_fused_kernel, dim3(nBlocksM), dim3(512), 0, stream, h, Bm, b1, P, nN);

  const int EDGE_BLOCKS = 2048;                   // 8 blocks/CU, full residency
  const int nw = EDGE_BLOCKS * 4;
  const int Q = (nE + 3) / 4;
  const int qpw = (Q + nw - 1) / nw;
  hipLaunchKernelGGL(edge_kernel, dim3(EDGE_BLOCKS), dim3(256), 0, stream, src, dst, P, W2, b2, out, nE, qpw);
}